// Round 5
// baseline (11566.948 us; speedup 1.0000x reference)
//
#include <hip/hip_runtime.h>
#include <hip/hip_bf16.h>
#include <math.h>

#define Hd 64
#define Fd 512
#define Cd 40
#define PCHUNK 512

typedef unsigned int uint;
typedef unsigned short ushort;

using bfrag   = __attribute__((ext_vector_type(8))) short;  // 8 bf16 = 4 VGPR
using floatx4 = __attribute__((ext_vector_type(4))) float;  // MFMA C/D

__device__ __forceinline__ float bcast(float v, int lane) {
  return __int_as_float(__builtin_amdgcn_readlane(__float_as_int(v), lane));
}
__device__ __forceinline__ ushort f2bf(float f) {
  union { float f; uint u; } c; c.f = f;
  uint r = c.u + 0x7fffu + ((c.u >> 16) & 1u);   // RNE
  return (ushort)(r >> 16);
}
__device__ __forceinline__ float bf2f(ushort s) {
  union { uint u; float f; } c; c.u = ((uint)s) << 16; return c.f;
}
__device__ __forceinline__ float bflo(uint u) { return __uint_as_float(u << 16); }
__device__ __forceinline__ float bfhi(uint u) { return __uint_as_float(u & 0xffff0000u); }

// ---------------- preprocessing (range-partitioned to keep atomic lines XCD-local) ----------------

__global__ __launch_bounds__(256) void count_kernel(const int* __restrict__ ei, int E,
                                                    int* __restrict__ outdeg,
                                                    int* __restrict__ indeg, int n) {
  int rg = blockIdx.x & 7;
  int lo = (int)(((long long)n * rg) >> 3);
  int hi = (int)(((long long)n * (rg + 1)) >> 3);
  int stride = (gridDim.x >> 3) * 256;
  for (int e = (blockIdx.x >> 3) * 256 + threadIdx.x; e < E; e += stride) {
    int s = __builtin_nontemporal_load(ei + e);
    int d = __builtin_nontemporal_load(ei + E + e);
    if (s >= lo && s < hi) atomicAdd(&outdeg[s], 1);
    if (d >= lo && d < hi) atomicAdd(&indeg[d], 1);
  }
}

__global__ void dinv_kernel(const int* __restrict__ outdeg, float* __restrict__ dinv, int n) {
  int i = blockIdx.x * blockDim.x + threadIdx.x;
  if (i < n) dinv[i] = rsqrtf((float)(outdeg[i] + 1));
}

__global__ __launch_bounds__(256) void pp_bsum(const int* __restrict__ counts, int n,
                                               int* __restrict__ bsum) {
  __shared__ int lds[256];
  int b = blockIdx.x, t = threadIdx.x;
  int i0 = b * PCHUNK + t;
  int s = 0;
  if (i0 < n) s += counts[i0];
  if (i0 + 256 < n) s += counts[i0 + 256];
  lds[t] = s; __syncthreads();
  for (int off = 128; off; off >>= 1) { if (t < off) lds[t] += lds[t + off]; __syncthreads(); }
  if (t == 0) bsum[b] = lds[0];
}

__global__ __launch_bounds__(256) void pp_bscan(const int* __restrict__ bsum, int nb,
                                                int* __restrict__ boff,
                                                int* __restrict__ row_ptr, int n) {
  __shared__ int lds[256];
  int t = threadIdx.x;
  int v = (t < nb) ? bsum[t] : 0;
  lds[t] = v; __syncthreads();
  for (int off = 1; off < 256; off <<= 1) {
    int x = (t >= off) ? lds[t - off] : 0;
    __syncthreads(); lds[t] += x; __syncthreads();
  }
  if (t < nb) boff[t] = lds[t] - v;
  if (t == 0) row_ptr[n] = lds[255];
}

__global__ __launch_bounds__(256) void pp_scan(const int* __restrict__ counts, int n,
                                               const int* __restrict__ boff,
                                               int* __restrict__ row_ptr,
                                               int* __restrict__ cursor) {
  __shared__ int lds[256];
  int b = blockIdx.x, t = threadIdx.x;
  int i0 = b * PCHUNK + 2 * t;
  int c0 = (i0 < n) ? counts[i0] : 0;
  int c1 = (i0 + 1 < n) ? counts[i0 + 1] : 0;
  int ps = c0 + c1;
  lds[t] = ps; __syncthreads();
  for (int off = 1; off < 256; off <<= 1) {
    int x = (t >= off) ? lds[t - off] : 0;
    __syncthreads(); lds[t] += x; __syncthreads();
  }
  int excl = lds[t] - ps + boff[b];
  if (i0 < n)     { row_ptr[i0] = excl;          cursor[i0] = excl; }
  if (i0 + 1 < n) { row_ptr[i0 + 1] = excl + c0; cursor[i0 + 1] = excl + c0; }
}

__global__ __launch_bounds__(256) void scatter_kernel(const int* __restrict__ ei, int E,
                                                      int* __restrict__ cursor,
                                                      int* __restrict__ esrc, int n) {
  int rg = blockIdx.x & 7;
  int lo = (int)(((long long)n * rg) >> 3);
  int hi = (int)(((long long)n * (rg + 1)) >> 3);
  int stride = (gridDim.x >> 3) * 256;
  for (int e = (blockIdx.x >> 3) * 256 + threadIdx.x; e < E; e += stride) {
    int d = __builtin_nontemporal_load(ei + E + e);
    if (d >= lo && d < hi) {
      int s = ei[e];
      int pos = atomicAdd(&cursor[d], 1);
      esrc[pos] = s;
    }
  }
}

// per-16-node-window degree rank sort -> worklist (degree-uniform wave groups)
__global__ __launch_bounds__(256) void sortwin_kernel(const int* __restrict__ indeg,
                                                      int* __restrict__ worklist, int n) {
  __shared__ int sd[256];
  int i = blockIdx.x * 256 + threadIdx.x;
  int deg = (i < n) ? indeg[i] : 0x7fffffff;
  sd[threadIdx.x] = deg;
  __syncthreads();
  int base = threadIdx.x & ~15;
  int li = threadIdx.x & 15;
  int rank = 0;
  #pragma unroll
  for (int j = 0; j < 16; ++j) {
    int dj = sd[base + j];
    rank += (int)((dj < deg) | ((dj == deg) & (j < li)));
  }
  worklist[blockIdx.x * 256 + base + rank] = i;
}

// ---------------- weight prep ----------------
__global__ void w0prep(const float* __restrict__ w0, ushort* __restrict__ w0T) {
  int i = blockIdx.x * 256 + threadIdx.x;
  if (i < Hd * Fd) {
    int o = i >> 9, k = i & 511;
    w0T[i] = f2bf(w0[(size_t)k * Hd + o]);
  }
}
__global__ void wprep(const float* __restrict__ wl, ushort* __restrict__ WT, int L) {
  int i = blockIdx.x * 256 + threadIdx.x;
  if (i < L * Hd * Hd) {
    int l = i >> 12, rem = i & 4095, o = rem >> 6, k = rem & 63;
    float beta = logf(0.5f / (float)(l + 1) + 1.f);
    float w = beta * wl[(size_t)l * 4096 + k * 64 + o];
    if (k == o) w += 1.f - beta;
    WT[i] = f2bf(w);
  }
}

// ---------------- input projection (MFMA, LDS-free) ----------------

__global__ __launch_bounds__(256) void gin_kernel(const float* __restrict__ x,
                                                  const ushort* __restrict__ w0T,
                                                  const float* __restrict__ b0,
                                                  const float* __restrict__ dinv,
                                                  ushort* __restrict__ h0q,
                                                  ushort* __restrict__ gq,
                                                  int n) {
  int wave = threadIdx.x >> 6;
  int lane = threadIdx.x & 63;
  int lrow = lane & 15;
  int lk   = lane >> 4;
  int nb   = blockIdx.x * 128 + wave * 32;

  floatx4 acc[2][4];
  #pragma unroll
  for (int m = 0; m < 2; ++m)
    #pragma unroll
    for (int o = 0; o < 4; ++o) acc[m][o] = floatx4{0.f, 0.f, 0.f, 0.f};

  for (int k0 = 0; k0 < Fd; k0 += 32) {
    bfrag a[2], b[4];
    #pragma unroll
    for (int m = 0; m < 2; ++m) {
      int node = nb + m * 16 + lrow; if (node >= n) node = n - 1;
      const float* px = x + (size_t)node * Fd + k0 + lk * 8;
      float4 lo = *(const float4*)px;
      float4 hi = *(const float4*)(px + 4);
      a[m][0] = (short)f2bf(lo.x); a[m][1] = (short)f2bf(lo.y);
      a[m][2] = (short)f2bf(lo.z); a[m][3] = (short)f2bf(lo.w);
      a[m][4] = (short)f2bf(hi.x); a[m][5] = (short)f2bf(hi.y);
      a[m][6] = (short)f2bf(hi.z); a[m][7] = (short)f2bf(hi.w);
    }
    #pragma unroll
    for (int o = 0; o < 4; ++o)
      b[o] = *(const bfrag*)(w0T + (size_t)(o * 16 + lrow) * Fd + k0 + lk * 8);
    #pragma unroll
    for (int m = 0; m < 2; ++m)
      #pragma unroll
      for (int o = 0; o < 4; ++o)
        acc[m][o] = __builtin_amdgcn_mfma_f32_16x16x32_bf16(a[m], b[o], acc[m][o], 0, 0, 0);
  }

  float b0v[4];
  #pragma unroll
  for (int o = 0; o < 4; ++o) b0v[o] = b0[o * 16 + lrow];

  #pragma unroll
  for (int m = 0; m < 2; ++m) {
    #pragma unroll
    for (int r = 0; r < 4; ++r) {
      int node = nb + m * 16 + lk * 4 + r;
      bool ok = node < n;
      int nn = ok ? node : 0;
      float dv = dinv[nn];
      #pragma unroll
      for (int o = 0; o < 4; ++o) {
        float v = fmaxf(acc[m][o][r] + b0v[o], 0.f);
        if (ok) {
          size_t idx = ((size_t)o * n + nn) * 16 + lrow;
          h0q[idx] = f2bf(v);
          gq[idx]  = f2bf(v * dv);
        }
      }
    }
  }
}

// ---------------- aggregation + support ----------------
// quarter = XCC_ID>>1 (hardware-derived); per-quarter atomic work queue + stealing
// guarantees completeness regardless of block->XCD mapping. Wave = 8 nodes x 8 lanes,
// processes one degree-sorted 16-node window (2 tasks) per pop. Streaming accesses NT.

__global__ __launch_bounds__(256) void agg_kernel(const ushort* __restrict__ gq,
                                                  const ushort* __restrict__ h0q,
                                                  const int* __restrict__ row_ptr,
                                                  const int* __restrict__ esrc,
                                                  const float* __restrict__ dinv,
                                                  const int* __restrict__ worklist,
                                                  int* __restrict__ qctr,
                                                  ushort* __restrict__ supq,
                                                  int n) {
  int lane = threadIdx.x & 63;
  int rl   = lane & 7;
  int grp  = lane >> 3;
  uint xcc;
  asm volatile("s_getreg_b32 %0, hwreg(HW_REG_XCC_ID)" : "=s"(xcc));
  int myq = (int)((xcc >> 1) & 3);
  int ntasks = (n + 7) >> 3;

  for (int attempt = 0; attempt < 4; ++attempt) {
    int q = (myq + attempt) & 3;
    const uint* gu = (const uint*)gq  + (size_t)q * n * 8;
    const uint* hu = (const uint*)h0q + (size_t)q * n * 8;
    uint*       su = (uint*)supq      + (size_t)q * n * 8;
    while (true) {
      int t0 = 0;
      if (lane == 0) t0 = atomicAdd(&qctr[q], 2);
      t0 = __shfl(t0, 0, 64);
      if (t0 >= ntasks) break;
      for (int w = 0; w < 2; ++w) {
        int tt = t0 + w;
        if (tt >= ntasks) break;
        int node = __builtin_nontemporal_load(worklist + tt * 8 + grp);
        bool ok = node < n;
        int nn = ok ? node : (n - 1);
        int e    = row_ptr[nn];
        int eend = ok ? row_ptr[nn + 1] : e;
        uint us = gu[(size_t)nn * 8 + rl];
        float aL[8], aH[8];
        aL[0] = bflo(us); aH[0] = bfhi(us);
        #pragma unroll
        for (int j = 1; j < 8; ++j) { aL[j] = 0.f; aH[j] = 0.f; }
        while (__any(e < eend)) {
          int sid[8];
          #pragma unroll
          for (int j = 0; j < 8; ++j)
            sid[j] = (e + j < eend) ? __builtin_nontemporal_load(esrc + e + j) : -1;
          #pragma unroll
          for (int j = 0; j < 8; ++j) {
            int s = sid[j] >= 0 ? sid[j] : 0;
            uint u = gu[(size_t)s * 8 + rl];
            if (sid[j] < 0) u = 0;
            aL[j] += bflo(u); aH[j] += bfhi(u);
          }
          e += 8;
        }
        float sumL = ((aL[0] + aL[1]) + (aL[2] + aL[3])) + ((aL[4] + aL[5]) + (aL[6] + aL[7]));
        float sumH = ((aH[0] + aH[1]) + (aH[2] + aH[3])) + ((aH[4] + aH[5]) + (aH[6] + aH[7]));
        float di = dinv[nn];
        uint h = __builtin_nontemporal_load(hu + (size_t)nn * 8 + rl);
        float s0v = 0.9f * di * sumL + 0.1f * bflo(h);
        float s1v = 0.9f * di * sumH + 0.1f * bfhi(h);
        if (ok)
          __builtin_nontemporal_store((uint)f2bf(s0v) | ((uint)f2bf(s1v) << 16),
                                      su + (size_t)nn * 8 + rl);
      }
    }
  }
}

// ---------------- layer matmul (MFMA) ----------------

__global__ __launch_bounds__(256) void mat_kernel(const ushort* __restrict__ supq,
                                                  const float* __restrict__ dinv,
                                                  const ushort* __restrict__ WT,
                                                  ushort* __restrict__ goutq,
                                                  int n) {
  int wave = threadIdx.x >> 6;
  int lane = threadIdx.x & 63;
  int lrow = lane & 15;
  int lk   = lane >> 4;
  int nb   = blockIdx.x * 128 + wave * 32;

  bfrag b[4][2];
  #pragma unroll
  for (int o = 0; o < 4; ++o)
    #pragma unroll
    for (int s = 0; s < 2; ++s)
      b[o][s] = *(const bfrag*)(WT + (size_t)(o * 16 + lrow) * 64 + s * 32 + lk * 8);

  floatx4 acc[2][4];
  #pragma unroll
  for (int m = 0; m < 2; ++m)
    #pragma unroll
    for (int o = 0; o < 4; ++o) acc[m][o] = floatx4{0.f, 0.f, 0.f, 0.f};

  #pragma unroll
  for (int m = 0; m < 2; ++m) {
    int node = nb + m * 16 + lrow; if (node >= n) node = n - 1;
    bfrag a0, a1;
    { int k = lk * 8;      a0 = *(const bfrag*)(supq + ((size_t)(k >> 4) * n + node) * 16 + (k & 15)); }
    { int k = 32 + lk * 8; a1 = *(const bfrag*)(supq + ((size_t)(k >> 4) * n + node) * 16 + (k & 15)); }
    #pragma unroll
    for (int o = 0; o < 4; ++o) {
      acc[m][o] = __builtin_amdgcn_mfma_f32_16x16x32_bf16(a0, b[o][0], acc[m][o], 0, 0, 0);
      acc[m][o] = __builtin_amdgcn_mfma_f32_16x16x32_bf16(a1, b[o][1], acc[m][o], 0, 0, 0);
    }
  }

  #pragma unroll
  for (int m = 0; m < 2; ++m) {
    #pragma unroll
    for (int r = 0; r < 4; ++r) {
      int node = nb + m * 16 + lk * 4 + r;
      bool ok = node < n;
      int nn = ok ? node : 0;
      float dv = dinv[nn];
      #pragma unroll
      for (int o = 0; o < 4; ++o) {
        float v = fmaxf(acc[m][o][r], 0.f);
        if (ok) goutq[((size_t)o * n + nn) * 16 + lrow] = f2bf(v * dv);
      }
    }
  }
}

// ---------------- head ----------------

__global__ __launch_bounds__(256) void final_kernel(const ushort* __restrict__ gq,
                                                    const int* __restrict__ outdeg,
                                                    const float* __restrict__ wf,
                                                    const float* __restrict__ bfv,
                                                    float* __restrict__ out, int n) {
  int lane = threadIdx.x & 63;
  int c = (lane < Cd) ? lane : 0;
  size_t qoff = (size_t)(lane >> 4) * n * 16 + (lane & 15);
  int gw = (int)((blockIdx.x * blockDim.x + threadIdx.x) >> 6);
  int nw = (int)((gridDim.x * blockDim.x) >> 6);
  for (int i = gw; i < n; i += nw) {
    float rdi = sqrtf((float)(outdeg[i] + 1));
    float hv = bf2f(gq[qoff + (size_t)i * 16]) * rdi;
    float acc = 0.f;
    #pragma unroll
    for (int k = 0; k < 64; ++k) acc += bcast(hv, k) * wf[k * Cd + c];
    float logit = acc + bfv[c];
    float m = (lane < Cd) ? logit : -1e30f;
    #pragma unroll
    for (int off = 32; off; off >>= 1) m = fmaxf(m, __shfl_xor(m, off, 64));
    float p = (lane < Cd) ? __expf(logit - m) : 0.f;
    #pragma unroll
    for (int off = 32; off; off >>= 1) p += __shfl_xor(p, off, 64);
    float lse = m + logf(p);
    if (lane < Cd) out[(size_t)i * Cd + lane] = logit - lse;
  }
}

// ---------------- launch ----------------

extern "C" void kernel_launch(void* const* d_in, const int* in_sizes, int n_in,
                              void* d_out, int out_size, void* d_ws, size_t ws_size,
                              hipStream_t stream) {
  const float* x  = (const float*)d_in[0];
  const int*   ei = (const int*)d_in[1];
  const float* w0 = (const float*)d_in[2];
  const float* b0 = (const float*)d_in[3];
  const float* wl = (const float*)d_in[4];
  const float* wf = (const float*)d_in[5];
  const float* bf = (const float*)d_in[6];
  int N = in_sizes[0] / Fd;
  int E = in_sizes[1] / 2;
  int L = in_sizes[4] / (Hd * Hd);
  float* out = (float*)d_out;

  char* w = (char*)d_ws;
  auto alloc = [&](size_t bytes) { char* p = w; w += (bytes + 255) & ~255ULL; return p; };
  int Npad = (N + 255) & ~255;
  int*    outdeg   = (int*)alloc((size_t)N * 4);
  int*    indeg    = (int*)alloc((size_t)N * 4);
  int*    row_ptr  = (int*)alloc((size_t)(N + 1) * 4);
  int*    cursor   = (int*)alloc((size_t)N * 4);
  float*  dinv     = (float*)alloc((size_t)N * 4);
  int*    bsum     = (int*)alloc(1024);
  int*    boff     = (int*)alloc(1024);
  int*    worklist = (int*)alloc((size_t)Npad * 4);
  int*    qctr     = (int*)alloc((size_t)L * 4 * 4);
  int*    esrc     = (int*)alloc((size_t)E * 4);
  ushort* w0T      = (ushort*)alloc((size_t)Hd * Fd * 2);
  ushort* WTall    = (ushort*)alloc((size_t)L * Hd * Hd * 2);
  ushort* h0q      = (ushort*)alloc((size_t)N * Hd * 2);
  ushort* gA       = (ushort*)alloc((size_t)N * Hd * 2);
  ushort* gB       = (ushort*)alloc((size_t)N * Hd * 2);
  ushort* supq     = (ushort*)alloc((size_t)N * Hd * 2);

  hipMemsetAsync(outdeg, 0, (size_t)N * 4, stream);
  hipMemsetAsync(indeg,  0, (size_t)N * 4, stream);
  hipMemsetAsync(qctr,   0, (size_t)L * 4 * 4, stream);

  int tb = 256;
  int nb = (N + PCHUNK - 1) / PCHUNK;
  count_kernel<<<2048, tb, 0, stream>>>(ei, E, outdeg, indeg, N);
  dinv_kernel<<<(N + tb - 1) / tb, tb, 0, stream>>>(outdeg, dinv, N);
  pp_bsum<<<nb, 256, 0, stream>>>(indeg, N, bsum);
  pp_bscan<<<1, 256, 0, stream>>>(bsum, nb, boff, row_ptr, N);
  pp_scan<<<nb, 256, 0, stream>>>(indeg, N, boff, row_ptr, cursor);
  scatter_kernel<<<2048, tb, 0, stream>>>(ei, E, cursor, esrc, N);
  sortwin_kernel<<<(Npad + 255) / 256, 256, 0, stream>>>(indeg, worklist, N);

  w0prep<<<(Hd * Fd + 255) / 256, 256, 0, stream>>>(w0, w0T);
  wprep<<<(L * Hd * Hd + 255) / 256, 256, 0, stream>>>(wl, WTall, L);

  int gemm_grid = (N + 127) / 128;
  gin_kernel<<<gemm_grid, 256, 0, stream>>>(x, w0T, b0, dinv, h0q, gA, N);

  ushort* cur = gA;
  ushort* bufs[2] = {gB, gA};
  for (int l = 0; l < L; ++l) {
    ushort* nxt = bufs[l & 1];
    agg_kernel<<<2048, 256, 0, stream>>>(cur, h0q, row_ptr, esrc, dinv, worklist,
                                         qctr + l * 4, supq, N);
    mat_kernel<<<gemm_grid, 256, 0, stream>>>(supq, dinv, WTall + (size_t)l * Hd * Hd, nxt, N);
    cur = nxt;
  }
  final_kernel<<<2048, 256, 0, stream>>>(cur, outdeg, wf, bf, out, N);
}

// Round 6
// 2081.699 us; speedup vs baseline: 5.5565x; 5.5565x over previous
//
#include <hip/hip_runtime.h>
#include <hip/hip_bf16.h>
#include <math.h>

#define Hd 64
#define Fd 512
#define Cd 40
#define PCHUNK 512

typedef unsigned int uint;
typedef unsigned short ushort;

using bfrag   = __attribute__((ext_vector_type(8))) short;  // 8 bf16 = 4 VGPR
using floatx4 = __attribute__((ext_vector_type(4))) float;  // MFMA C/D

__device__ __forceinline__ float bcast(float v, int lane) {
  return __int_as_float(__builtin_amdgcn_readlane(__float_as_int(v), lane));
}
__device__ __forceinline__ ushort f2bf(float f) {
  union { float f; uint u; } c; c.f = f;
  uint r = c.u + 0x7fffu + ((c.u >> 16) & 1u);   // RNE
  return (ushort)(r >> 16);
}
__device__ __forceinline__ float bf2f(ushort s) {
  union { uint u; float f; } c; c.u = ((uint)s) << 16; return c.f;
}
__device__ __forceinline__ float bflo(uint u) { return __uint_as_float(u << 16); }
__device__ __forceinline__ float bfhi(uint u) { return __uint_as_float(u & 0xffff0000u); }

// ---------------- preprocessing (range-partitioned to keep atomic lines XCD-local) ----------------

__global__ __launch_bounds__(256) void count_kernel(const int* __restrict__ ei, int E,
                                                    int* __restrict__ outdeg,
                                                    int* __restrict__ indeg, int n) {
  int rg = blockIdx.x & 7;
  int lo = (int)(((long long)n * rg) >> 3);
  int hi = (int)(((long long)n * (rg + 1)) >> 3);
  int stride = (gridDim.x >> 3) * 256;
  for (int e = (blockIdx.x >> 3) * 256 + threadIdx.x; e < E; e += stride) {
    int s = __builtin_nontemporal_load(ei + e);
    int d = __builtin_nontemporal_load(ei + E + e);
    if (s >= lo && s < hi) atomicAdd(&outdeg[s], 1);
    if (d >= lo && d < hi) atomicAdd(&indeg[d], 1);
  }
}

__global__ void dinv_kernel(const int* __restrict__ outdeg, float* __restrict__ dinv, int n) {
  int i = blockIdx.x * blockDim.x + threadIdx.x;
  if (i < n) dinv[i] = rsqrtf((float)(outdeg[i] + 1));
}

__global__ __launch_bounds__(256) void pp_bsum(const int* __restrict__ counts, int n,
                                               int* __restrict__ bsum) {
  __shared__ int lds[256];
  int b = blockIdx.x, t = threadIdx.x;
  int i0 = b * PCHUNK + t;
  int s = 0;
  if (i0 < n) s += counts[i0];
  if (i0 + 256 < n) s += counts[i0 + 256];
  lds[t] = s; __syncthreads();
  for (int off = 128; off; off >>= 1) { if (t < off) lds[t] += lds[t + off]; __syncthreads(); }
  if (t == 0) bsum[b] = lds[0];
}

__global__ __launch_bounds__(256) void pp_bscan(const int* __restrict__ bsum, int nb,
                                                int* __restrict__ boff,
                                                int* __restrict__ row_ptr, int n) {
  __shared__ int lds[256];
  int t = threadIdx.x;
  int v = (t < nb) ? bsum[t] : 0;
  lds[t] = v; __syncthreads();
  for (int off = 1; off < 256; off <<= 1) {
    int x = (t >= off) ? lds[t - off] : 0;
    __syncthreads(); lds[t] += x; __syncthreads();
  }
  if (t < nb) boff[t] = lds[t] - v;
  if (t == 0) row_ptr[n] = lds[255];
}

__global__ __launch_bounds__(256) void pp_scan(const int* __restrict__ counts, int n,
                                               const int* __restrict__ boff,
                                               int* __restrict__ row_ptr,
                                               int* __restrict__ cursor) {
  __shared__ int lds[256];
  int b = blockIdx.x, t = threadIdx.x;
  int i0 = b * PCHUNK + 2 * t;
  int c0 = (i0 < n) ? counts[i0] : 0;
  int c1 = (i0 + 1 < n) ? counts[i0 + 1] : 0;
  int ps = c0 + c1;
  lds[t] = ps; __syncthreads();
  for (int off = 1; off < 256; off <<= 1) {
    int x = (t >= off) ? lds[t - off] : 0;
    __syncthreads(); lds[t] += x; __syncthreads();
  }
  int excl = lds[t] - ps + boff[b];
  if (i0 < n)     { row_ptr[i0] = excl;          cursor[i0] = excl; }
  if (i0 + 1 < n) { row_ptr[i0 + 1] = excl + c0; cursor[i0 + 1] = excl + c0; }
}

__global__ __launch_bounds__(256) void scatter_kernel(const int* __restrict__ ei, int E,
                                                      int* __restrict__ cursor,
                                                      int* __restrict__ esrc, int n) {
  int rg = blockIdx.x & 7;
  int lo = (int)(((long long)n * rg) >> 3);
  int hi = (int)(((long long)n * (rg + 1)) >> 3);
  int stride = (gridDim.x >> 3) * 256;
  for (int e = (blockIdx.x >> 3) * 256 + threadIdx.x; e < E; e += stride) {
    int d = __builtin_nontemporal_load(ei + E + e);
    if (d >= lo && d < hi) {
      int s = ei[e];
      int pos = atomicAdd(&cursor[d], 1);
      esrc[pos] = s;
    }
  }
}

// per-8-node-window degree rank sort -> worklist (one degree-uniform window per wave)
__global__ __launch_bounds__(256) void sortwin_kernel(const int* __restrict__ indeg,
                                                      int* __restrict__ worklist, int n) {
  __shared__ int sd[256];
  int i = blockIdx.x * 256 + threadIdx.x;
  int deg = (i < n) ? indeg[i] : 0x7fffffff;
  sd[threadIdx.x] = deg;
  __syncthreads();
  int base = threadIdx.x & ~7;
  int li = threadIdx.x & 7;
  int rank = 0;
  #pragma unroll
  for (int j = 0; j < 8; ++j) {
    int dj = sd[base + j];
    rank += (int)((dj < deg) | ((dj == deg) & (j < li)));
  }
  worklist[blockIdx.x * 256 + base + rank] = i;
}

// ---------------- weight prep ----------------
__global__ void w0prep(const float* __restrict__ w0, ushort* __restrict__ w0T) {
  int i = blockIdx.x * 256 + threadIdx.x;
  if (i < Hd * Fd) {
    int o = i >> 9, k = i & 511;
    w0T[i] = f2bf(w0[(size_t)k * Hd + o]);
  }
}
__global__ void wprep(const float* __restrict__ wl, ushort* __restrict__ WT, int L) {
  int i = blockIdx.x * 256 + threadIdx.x;
  if (i < L * Hd * Hd) {
    int l = i >> 12, rem = i & 4095, o = rem >> 6, k = rem & 63;
    float beta = logf(0.5f / (float)(l + 1) + 1.f);
    float w = beta * wl[(size_t)l * 4096 + k * 64 + o];
    if (k == o) w += 1.f - beta;
    WT[i] = f2bf(w);
  }
}

// ---------------- input projection (MFMA, LDS-free) ----------------

__global__ __launch_bounds__(256) void gin_kernel(const float* __restrict__ x,
                                                  const ushort* __restrict__ w0T,
                                                  const float* __restrict__ b0,
                                                  const float* __restrict__ dinv,
                                                  ushort* __restrict__ h0q,
                                                  ushort* __restrict__ gq,
                                                  int n) {
  int wave = threadIdx.x >> 6;
  int lane = threadIdx.x & 63;
  int lrow = lane & 15;
  int lk   = lane >> 4;
  int nb   = blockIdx.x * 128 + wave * 32;

  floatx4 acc[2][4];
  #pragma unroll
  for (int m = 0; m < 2; ++m)
    #pragma unroll
    for (int o = 0; o < 4; ++o) acc[m][o] = floatx4{0.f, 0.f, 0.f, 0.f};

  for (int k0 = 0; k0 < Fd; k0 += 32) {
    bfrag a[2], b[4];
    #pragma unroll
    for (int m = 0; m < 2; ++m) {
      int node = nb + m * 16 + lrow; if (node >= n) node = n - 1;
      const float* px = x + (size_t)node * Fd + k0 + lk * 8;
      float4 lo = *(const float4*)px;
      float4 hi = *(const float4*)(px + 4);
      a[m][0] = (short)f2bf(lo.x); a[m][1] = (short)f2bf(lo.y);
      a[m][2] = (short)f2bf(lo.z); a[m][3] = (short)f2bf(lo.w);
      a[m][4] = (short)f2bf(hi.x); a[m][5] = (short)f2bf(hi.y);
      a[m][6] = (short)f2bf(hi.z); a[m][7] = (short)f2bf(hi.w);
    }
    #pragma unroll
    for (int o = 0; o < 4; ++o)
      b[o] = *(const bfrag*)(w0T + (size_t)(o * 16 + lrow) * Fd + k0 + lk * 8);
    #pragma unroll
    for (int m = 0; m < 2; ++m)
      #pragma unroll
      for (int o = 0; o < 4; ++o)
        acc[m][o] = __builtin_amdgcn_mfma_f32_16x16x32_bf16(a[m], b[o], acc[m][o], 0, 0, 0);
  }

  float b0v[4];
  #pragma unroll
  for (int o = 0; o < 4; ++o) b0v[o] = b0[o * 16 + lrow];

  #pragma unroll
  for (int m = 0; m < 2; ++m) {
    #pragma unroll
    for (int r = 0; r < 4; ++r) {
      int node = nb + m * 16 + lk * 4 + r;
      bool ok = node < n;
      int nn = ok ? node : 0;
      float dv = dinv[nn];
      #pragma unroll
      for (int o = 0; o < 4; ++o) {
        float v = fmaxf(acc[m][o][r] + b0v[o], 0.f);
        if (ok) {
          size_t idx = ((size_t)o * n + nn) * 16 + lrow;
          h0q[idx] = f2bf(v);
          gq[idx]  = f2bf(v * dv);
        }
      }
    }
  }
}

// ---------------- aggregation + support ----------------
// Static partition, NO atomics: quarter q = (blockIdx&7)>>1 (bets bid%8=XCD for L2
// locality; correct regardless). Wave = one degree-sorted 8-node window; lane group
// of 8 covers the 32B quarter-row. 1-deep prefetch pipeline on the esrc->gather chain.
// NT on streaming data (esrc, h0, sup store) to protect slab L2 residency.

__global__ __launch_bounds__(256) void agg_kernel(const ushort* __restrict__ gq,
                                                  const ushort* __restrict__ h0q,
                                                  const int* __restrict__ row_ptr,
                                                  const int* __restrict__ esrc,
                                                  const float* __restrict__ dinv,
                                                  const int* __restrict__ worklist,
                                                  ushort* __restrict__ supq,
                                                  int n) {
  int lane = threadIdx.x & 63;
  int dw   = lane & 7;         // dword within 32B quarter-row
  int grp  = lane >> 3;        // node slot 0..7
  int q      = (blockIdx.x & 7) >> 1;
  int blkInQ = ((blockIdx.x >> 3) << 1) | (blockIdx.x & 1);
  int wv  = blkInQ * 4 + (threadIdx.x >> 6);
  int nwv = (gridDim.x >> 2) * 4;   // waves per quarter

  const uint* gu = (const uint*)gq  + (size_t)q * n * 8;
  const uint* hu = (const uint*)h0q + (size_t)q * n * 8;
  uint*       su = (uint*)supq      + (size_t)q * n * 8;

  int nwin = (n + 7) >> 3;
  for (int w = wv; w < nwin; w += nwv) {
    int node = worklist[w * 8 + grp];
    bool ok = node < n;
    int nn = ok ? node : (n - 1);
    int e    = row_ptr[nn];
    int eend = ok ? row_ptr[nn + 1] : e;
    uint us = gu[(size_t)nn * 8 + dw];
    float aL0 = bflo(us), aH0 = bfhi(us);
    float aL1 = 0.f, aH1 = 0.f, aL2 = 0.f, aH2 = 0.f, aL3 = 0.f, aH3 = 0.f;
    int s0 = (e     < eend) ? __builtin_nontemporal_load(esrc + e)     : -1;
    int s1 = (e + 1 < eend) ? __builtin_nontemporal_load(esrc + e + 1) : -1;
    int s2 = (e + 2 < eend) ? __builtin_nontemporal_load(esrc + e + 2) : -1;
    int s3 = (e + 3 < eend) ? __builtin_nontemporal_load(esrc + e + 3) : -1;
    while (__any(e < eend)) {
      int e4 = e + 4;
      int t0 = (e4     < eend) ? __builtin_nontemporal_load(esrc + e4)     : -1;
      int t1 = (e4 + 1 < eend) ? __builtin_nontemporal_load(esrc + e4 + 1) : -1;
      int t2 = (e4 + 2 < eend) ? __builtin_nontemporal_load(esrc + e4 + 2) : -1;
      int t3 = (e4 + 3 < eend) ? __builtin_nontemporal_load(esrc + e4 + 3) : -1;
      uint u0 = gu[(size_t)(s0 >= 0 ? s0 : 0) * 8 + dw]; if (s0 < 0) u0 = 0;
      uint u1 = gu[(size_t)(s1 >= 0 ? s1 : 0) * 8 + dw]; if (s1 < 0) u1 = 0;
      uint u2 = gu[(size_t)(s2 >= 0 ? s2 : 0) * 8 + dw]; if (s2 < 0) u2 = 0;
      uint u3 = gu[(size_t)(s3 >= 0 ? s3 : 0) * 8 + dw]; if (s3 < 0) u3 = 0;
      aL0 += bflo(u0); aH0 += bfhi(u0);
      aL1 += bflo(u1); aH1 += bfhi(u1);
      aL2 += bflo(u2); aH2 += bfhi(u2);
      aL3 += bflo(u3); aH3 += bfhi(u3);
      s0 = t0; s1 = t1; s2 = t2; s3 = t3;
      e = e4;
    }
    float sumL = (aL0 + aL1) + (aL2 + aL3);
    float sumH = (aH0 + aH1) + (aH2 + aH3);
    float di = dinv[nn];
    uint h = __builtin_nontemporal_load(hu + (size_t)nn * 8 + dw);
    float v0 = 0.9f * di * sumL + 0.1f * bflo(h);
    float v1 = 0.9f * di * sumH + 0.1f * bfhi(h);
    if (ok)
      __builtin_nontemporal_store((uint)f2bf(v0) | ((uint)f2bf(v1) << 16),
                                  su + (size_t)nn * 8 + dw);
  }
}

// ---------------- layer matmul (MFMA) ----------------

__global__ __launch_bounds__(256) void mat_kernel(const ushort* __restrict__ supq,
                                                  const float* __restrict__ dinv,
                                                  const ushort* __restrict__ WT,
                                                  ushort* __restrict__ goutq,
                                                  int n) {
  int wave = threadIdx.x >> 6;
  int lane = threadIdx.x & 63;
  int lrow = lane & 15;
  int lk   = lane >> 4;
  int nb   = blockIdx.x * 128 + wave * 32;

  bfrag b[4][2];
  #pragma unroll
  for (int o = 0; o < 4; ++o)
    #pragma unroll
    for (int s = 0; s < 2; ++s)
      b[o][s] = *(const bfrag*)(WT + (size_t)(o * 16 + lrow) * 64 + s * 32 + lk * 8);

  floatx4 acc[2][4];
  #pragma unroll
  for (int m = 0; m < 2; ++m)
    #pragma unroll
    for (int o = 0; o < 4; ++o) acc[m][o] = floatx4{0.f, 0.f, 0.f, 0.f};

  #pragma unroll
  for (int m = 0; m < 2; ++m) {
    int node = nb + m * 16 + lrow; if (node >= n) node = n - 1;
    bfrag a0, a1;
    { int k = lk * 8;      a0 = *(const bfrag*)(supq + ((size_t)(k >> 4) * n + node) * 16 + (k & 15)); }
    { int k = 32 + lk * 8; a1 = *(const bfrag*)(supq + ((size_t)(k >> 4) * n + node) * 16 + (k & 15)); }
    #pragma unroll
    for (int o = 0; o < 4; ++o) {
      acc[m][o] = __builtin_amdgcn_mfma_f32_16x16x32_bf16(a0, b[o][0], acc[m][o], 0, 0, 0);
      acc[m][o] = __builtin_amdgcn_mfma_f32_16x16x32_bf16(a1, b[o][1], acc[m][o], 0, 0, 0);
    }
  }

  #pragma unroll
  for (int m = 0; m < 2; ++m) {
    #pragma unroll
    for (int r = 0; r < 4; ++r) {
      int node = nb + m * 16 + lk * 4 + r;
      bool ok = node < n;
      int nn = ok ? node : 0;
      float dv = dinv[nn];
      #pragma unroll
      for (int o = 0; o < 4; ++o) {
        float v = fmaxf(acc[m][o][r], 0.f);
        if (ok) goutq[((size_t)o * n + nn) * 16 + lrow] = f2bf(v * dv);
      }
    }
  }
}

// ---------------- head ----------------

__global__ __launch_bounds__(256) void final_kernel(const ushort* __restrict__ gq,
                                                    const int* __restrict__ outdeg,
                                                    const float* __restrict__ wf,
                                                    const float* __restrict__ bfv,
                                                    float* __restrict__ out, int n) {
  int lane = threadIdx.x & 63;
  int c = (lane < Cd) ? lane : 0;
  size_t qoff = (size_t)(lane >> 4) * n * 16 + (lane & 15);
  int gw = (int)((blockIdx.x * blockDim.x + threadIdx.x) >> 6);
  int nw = (int)((gridDim.x * blockDim.x) >> 6);
  for (int i = gw; i < n; i += nw) {
    float rdi = sqrtf((float)(outdeg[i] + 1));
    float hv = bf2f(gq[qoff + (size_t)i * 16]) * rdi;
    float acc = 0.f;
    #pragma unroll
    for (int k = 0; k < 64; ++k) acc += bcast(hv, k) * wf[k * Cd + c];
    float logit = acc + bfv[c];
    float m = (lane < Cd) ? logit : -1e30f;
    #pragma unroll
    for (int off = 32; off; off >>= 1) m = fmaxf(m, __shfl_xor(m, off, 64));
    float p = (lane < Cd) ? __expf(logit - m) : 0.f;
    #pragma unroll
    for (int off = 32; off; off >>= 1) p += __shfl_xor(p, off, 64);
    float lse = m + logf(p);
    if (lane < Cd) out[(size_t)i * Cd + lane] = logit - lse;
  }
}

// ---------------- launch ----------------

extern "C" void kernel_launch(void* const* d_in, const int* in_sizes, int n_in,
                              void* d_out, int out_size, void* d_ws, size_t ws_size,
                              hipStream_t stream) {
  const float* x  = (const float*)d_in[0];
  const int*   ei = (const int*)d_in[1];
  const float* w0 = (const float*)d_in[2];
  const float* b0 = (const float*)d_in[3];
  const float* wl = (const float*)d_in[4];
  const float* wf = (const float*)d_in[5];
  const float* bf = (const float*)d_in[6];
  int N = in_sizes[0] / Fd;
  int E = in_sizes[1] / 2;
  int L = in_sizes[4] / (Hd * Hd);
  float* out = (float*)d_out;

  char* w = (char*)d_ws;
  auto alloc = [&](size_t bytes) { char* p = w; w += (bytes + 255) & ~255ULL; return p; };
  int Npad = (N + 255) & ~255;
  int*    outdeg   = (int*)alloc((size_t)N * 4);
  int*    indeg    = (int*)alloc((size_t)N * 4);
  int*    row_ptr  = (int*)alloc((size_t)(N + 1) * 4);
  int*    cursor   = (int*)alloc((size_t)N * 4);
  float*  dinv     = (float*)alloc((size_t)N * 4);
  int*    bsum     = (int*)alloc(1024);
  int*    boff     = (int*)alloc(1024);
  int*    worklist = (int*)alloc((size_t)Npad * 4);
  int*    esrc     = (int*)alloc((size_t)E * 4);
  ushort* w0T      = (ushort*)alloc((size_t)Hd * Fd * 2);
  ushort* WTall    = (ushort*)alloc((size_t)L * Hd * Hd * 2);
  ushort* h0q      = (ushort*)alloc((size_t)N * Hd * 2);
  ushort* gA       = (ushort*)alloc((size_t)N * Hd * 2);
  ushort* gB       = (ushort*)alloc((size_t)N * Hd * 2);
  ushort* supq     = (ushort*)alloc((size_t)N * Hd * 2);

  hipMemsetAsync(outdeg, 0, (size_t)N * 4, stream);
  hipMemsetAsync(indeg,  0, (size_t)N * 4, stream);

  int tb = 256;
  int nb = (N + PCHUNK - 1) / PCHUNK;
  count_kernel<<<2048, tb, 0, stream>>>(ei, E, outdeg, indeg, N);
  dinv_kernel<<<(N + tb - 1) / tb, tb, 0, stream>>>(outdeg, dinv, N);
  pp_bsum<<<nb, 256, 0, stream>>>(indeg, N, bsum);
  pp_bscan<<<1, 256, 0, stream>>>(bsum, nb, boff, row_ptr, N);
  pp_scan<<<nb, 256, 0, stream>>>(indeg, N, boff, row_ptr, cursor);
  scatter_kernel<<<2048, tb, 0, stream>>>(ei, E, cursor, esrc, N);
  sortwin_kernel<<<(Npad + 255) / 256, 256, 0, stream>>>(indeg, worklist, N);

  w0prep<<<(Hd * Fd + 255) / 256, 256, 0, stream>>>(w0, w0T);
  wprep<<<(L * Hd * Hd + 255) / 256, 256, 0, stream>>>(wl, WTall, L);

  int gemm_grid = (N + 127) / 128;
  gin_kernel<<<gemm_grid, 256, 0, stream>>>(x, w0T, b0, dinv, h0q, gA, N);

  ushort* cur = gA;
  ushort* bufs[2] = {gB, gA};
  for (int l = 0; l < L; ++l) {
    ushort* nxt = bufs[l & 1];
    agg_kernel<<<2048, 256, 0, stream>>>(cur, h0q, row_ptr, esrc, dinv, worklist,
                                         supq, N);
    mat_kernel<<<gemm_grid, 256, 0, stream>>>(supq, dinv, WTall + (size_t)l * Hd * Hd, nxt, N);
    cur = nxt;
  }
  final_kernel<<<2048, 256, 0, stream>>>(cur, outdeg, wf, bf, out, N);
}

// Round 7
// 1451.812 us; speedup vs baseline: 7.9673x; 1.4339x over previous
//
#include <hip/hip_runtime.h>
#include <hip/hip_bf16.h>
#include <math.h>

#define Hd 64
#define Fd 512
#define Cd 40
#define PCHUNK 512

typedef unsigned int uint;
typedef unsigned short ushort;

using bfrag   = __attribute__((ext_vector_type(8))) short;  // 8 bf16 = 4 VGPR
using floatx4 = __attribute__((ext_vector_type(4))) float;  // MFMA C/D

__device__ __forceinline__ float bcast(float v, int lane) {
  return __int_as_float(__builtin_amdgcn_readlane(__float_as_int(v), lane));
}
__device__ __forceinline__ ushort f2bf(float f) {
  union { float f; uint u; } c; c.f = f;
  uint r = c.u + 0x7fffu + ((c.u >> 16) & 1u);   // RNE
  return (ushort)(r >> 16);
}
__device__ __forceinline__ float bf2f(ushort s) {
  union { uint u; float f; } c; c.u = ((uint)s) << 16; return c.f;
}
__device__ __forceinline__ float bflo(uint u) { return __uint_as_float(u << 16); }
__device__ __forceinline__ float bfhi(uint u) { return __uint_as_float(u & 0xffff0000u); }

// ---------------- degree count: LDS byte-histograms, zero global atomics ----------------
// 128 blocks: class = b>>5 in {0..3} = dir*2 + range; chunk c = b&31.
// dir0 = indeg (dst array), dir1 = outdeg (src array). Each block histograms its
// edge chunk for its node half-range into 50KB LDS (uchar packed in uint), then
// writes the partial histogram coalesced. degred_kernel column-sums the partials.

__global__ __launch_bounds__(256) void hist_kernel(const int* __restrict__ ei, int E,
                                                   uint* __restrict__ partials,
                                                   int n, int RH, int NW, int CH) {
  __shared__ uint hist[12544];   // up to 50176 nodes per half-range
  int b = blockIdx.x;
  int cls = b >> 5;
  int c   = b & 31;
  int dir = cls >> 1, r = cls & 1;
  const int* arr = dir ? ei : (ei + E);
  int lo = r * RH, hi = n < lo + RH ? n : lo + RH;
  int e0 = c * CH, e1 = E < e0 + CH ? E : e0 + CH;
  for (int i = threadIdx.x; i < NW; i += 256) hist[i] = 0;
  __syncthreads();
  for (int e = e0 + threadIdx.x; e < e1; e += 256) {
    int d = __builtin_nontemporal_load(arr + e);
    if (d >= lo && d < hi) {
      int ld = d - lo;
      atomicAdd(&hist[ld >> 2], 1u << ((ld & 3) << 3));
    }
  }
  __syncthreads();
  uint* out = partials + (size_t)b * NW;
  for (int i = threadIdx.x; i < NW; i += 256) out[i] = hist[i];
}

__global__ __launch_bounds__(256) void degred_kernel(const uint* __restrict__ partials,
                                                     int n, int RH, int NW,
                                                     int* __restrict__ indeg,
                                                     int* __restrict__ outdeg,
                                                     float* __restrict__ dinv) {
  int d = blockIdx.x * 256 + threadIdx.x;
  if (d >= n) return;
  int r = (d >= RH) ? 1 : 0;
  int ld = d - r * RH;
  int wd = ld >> 2, sh = (ld & 3) << 3;
  const uint* pIn  = partials + (size_t)(r)     * 32 * NW + wd;
  const uint* pOut = partials + (size_t)(2 + r) * 32 * NW + wd;
  uint sIn = 0, sOut = 0;
  #pragma unroll 8
  for (int c = 0; c < 32; ++c) {
    sIn  += (pIn [(size_t)c * NW] >> sh) & 0xffu;
    sOut += (pOut[(size_t)c * NW] >> sh) & 0xffu;
  }
  indeg[d] = (int)sIn;
  outdeg[d] = (int)sOut;
  dinv[d] = rsqrtf((float)(sOut + 1u));
}

// fallback (unexpected problem size): plain atomic count
__global__ void count_fallback(const int* __restrict__ ei, int E,
                               int* __restrict__ outdeg, int* __restrict__ indeg) {
  int e = blockIdx.x * blockDim.x + threadIdx.x;
  if (e < E) {
    atomicAdd(&outdeg[ei[e]], 1);
    atomicAdd(&indeg[ei[E + e]], 1);
  }
}
__global__ void dinv_fallback(const int* __restrict__ outdeg, float* __restrict__ dinv, int n) {
  int i = blockIdx.x * blockDim.x + threadIdx.x;
  if (i < n) dinv[i] = rsqrtf((float)(outdeg[i] + 1));
}

// ---------------- prefix scans for CSR ----------------

__global__ __launch_bounds__(256) void pp_bsum(const int* __restrict__ counts, int n,
                                               int* __restrict__ bsum) {
  __shared__ int lds[256];
  int b = blockIdx.x, t = threadIdx.x;
  int i0 = b * PCHUNK + t;
  int s = 0;
  if (i0 < n) s += counts[i0];
  if (i0 + 256 < n) s += counts[i0 + 256];
  lds[t] = s; __syncthreads();
  for (int off = 128; off; off >>= 1) { if (t < off) lds[t] += lds[t + off]; __syncthreads(); }
  if (t == 0) bsum[b] = lds[0];
}

__global__ __launch_bounds__(256) void pp_bscan(const int* __restrict__ bsum, int nb,
                                                int* __restrict__ boff,
                                                int* __restrict__ row_ptr, int n) {
  __shared__ int lds[256];
  int t = threadIdx.x;
  int v = (t < nb) ? bsum[t] : 0;
  lds[t] = v; __syncthreads();
  for (int off = 1; off < 256; off <<= 1) {
    int x = (t >= off) ? lds[t - off] : 0;
    __syncthreads(); lds[t] += x; __syncthreads();
  }
  if (t < nb) boff[t] = lds[t] - v;
  if (t == 0) row_ptr[n] = lds[255];
}

__global__ __launch_bounds__(256) void pp_scan(const int* __restrict__ counts, int n,
                                               const int* __restrict__ boff,
                                               int* __restrict__ row_ptr,
                                               int* __restrict__ cursor) {
  __shared__ int lds[256];
  int b = blockIdx.x, t = threadIdx.x;
  int i0 = b * PCHUNK + 2 * t;
  int c0 = (i0 < n) ? counts[i0] : 0;
  int c1 = (i0 + 1 < n) ? counts[i0 + 1] : 0;
  int ps = c0 + c1;
  lds[t] = ps; __syncthreads();
  for (int off = 1; off < 256; off <<= 1) {
    int x = (t >= off) ? lds[t - off] : 0;
    __syncthreads(); lds[t] += x; __syncthreads();
  }
  int excl = lds[t] - ps + boff[b];
  if (i0 < n)     { row_ptr[i0] = excl;          cursor[i0] = excl; }
  if (i0 + 1 < n) { row_ptr[i0 + 1] = excl + c0; cursor[i0 + 1] = excl + c0; }
}

__global__ __launch_bounds__(256) void scatter_kernel(const int* __restrict__ ei, int E,
                                                      int* __restrict__ cursor,
                                                      int* __restrict__ esrc, int n) {
  int rg = blockIdx.x & 7;
  int lo = (int)(((long long)n * rg) >> 3);
  int hi = (int)(((long long)n * (rg + 1)) >> 3);
  int stride = (gridDim.x >> 3) * 256;
  for (int e = (blockIdx.x >> 3) * 256 + threadIdx.x; e < E; e += stride) {
    int d = __builtin_nontemporal_load(ei + E + e);
    if (d >= lo && d < hi) {
      int s = ei[e];
      int pos = atomicAdd(&cursor[d], 1);
      esrc[pos] = s;
    }
  }
}

// per-8-node-window degree rank sort -> worklist (one degree-uniform window per wave)
__global__ __launch_bounds__(256) void sortwin_kernel(const int* __restrict__ indeg,
                                                      int* __restrict__ worklist, int n) {
  __shared__ int sd[256];
  int i = blockIdx.x * 256 + threadIdx.x;
  int deg = (i < n) ? indeg[i] : 0x7fffffff;
  sd[threadIdx.x] = deg;
  __syncthreads();
  int base = threadIdx.x & ~7;
  int li = threadIdx.x & 7;
  int rank = 0;
  #pragma unroll
  for (int j = 0; j < 8; ++j) {
    int dj = sd[base + j];
    rank += (int)((dj < deg) | ((dj == deg) & (j < li)));
  }
  worklist[blockIdx.x * 256 + base + rank] = i;
}

// ---------------- weight prep ----------------
__global__ void w0prep(const float* __restrict__ w0, ushort* __restrict__ w0T) {
  int i = blockIdx.x * 256 + threadIdx.x;
  if (i < Hd * Fd) {
    int o = i >> 9, k = i & 511;
    w0T[i] = f2bf(w0[(size_t)k * Hd + o]);
  }
}
__global__ void wprep(const float* __restrict__ wl, ushort* __restrict__ WT, int L) {
  int i = blockIdx.x * 256 + threadIdx.x;
  if (i < L * Hd * Hd) {
    int l = i >> 12, rem = i & 4095, o = rem >> 6, k = rem & 63;
    float beta = logf(0.5f / (float)(l + 1) + 1.f);
    float w = beta * wl[(size_t)l * 4096 + k * 64 + o];
    if (k == o) w += 1.f - beta;
    WT[i] = f2bf(w);
  }
}

// ---------------- input projection (MFMA, LDS-free); row-major outputs ----------------

__global__ __launch_bounds__(256) void gin_kernel(const float* __restrict__ x,
                                                  const ushort* __restrict__ w0T,
                                                  const float* __restrict__ b0,
                                                  const float* __restrict__ dinv,
                                                  ushort* __restrict__ h0r,
                                                  ushort* __restrict__ gr,
                                                  int n) {
  int wave = threadIdx.x >> 6;
  int lane = threadIdx.x & 63;
  int lrow = lane & 15;
  int lk   = lane >> 4;
  int nb   = blockIdx.x * 128 + wave * 32;

  floatx4 acc[2][4];
  #pragma unroll
  for (int m = 0; m < 2; ++m)
    #pragma unroll
    for (int o = 0; o < 4; ++o) acc[m][o] = floatx4{0.f, 0.f, 0.f, 0.f};

  for (int k0 = 0; k0 < Fd; k0 += 32) {
    bfrag a[2], b[4];
    #pragma unroll
    for (int m = 0; m < 2; ++m) {
      int node = nb + m * 16 + lrow; if (node >= n) node = n - 1;
      const float* px = x + (size_t)node * Fd + k0 + lk * 8;
      float4 lo = *(const float4*)px;
      float4 hi = *(const float4*)(px + 4);
      a[m][0] = (short)f2bf(lo.x); a[m][1] = (short)f2bf(lo.y);
      a[m][2] = (short)f2bf(lo.z); a[m][3] = (short)f2bf(lo.w);
      a[m][4] = (short)f2bf(hi.x); a[m][5] = (short)f2bf(hi.y);
      a[m][6] = (short)f2bf(hi.z); a[m][7] = (short)f2bf(hi.w);
    }
    #pragma unroll
    for (int o = 0; o < 4; ++o)
      b[o] = *(const bfrag*)(w0T + (size_t)(o * 16 + lrow) * Fd + k0 + lk * 8);
    #pragma unroll
    for (int m = 0; m < 2; ++m)
      #pragma unroll
      for (int o = 0; o < 4; ++o)
        acc[m][o] = __builtin_amdgcn_mfma_f32_16x16x32_bf16(a[m], b[o], acc[m][o], 0, 0, 0);
  }

  float b0v[4];
  #pragma unroll
  for (int o = 0; o < 4; ++o) b0v[o] = b0[o * 16 + lrow];

  #pragma unroll
  for (int m = 0; m < 2; ++m) {
    #pragma unroll
    for (int r = 0; r < 4; ++r) {
      int node = nb + m * 16 + lk * 4 + r;
      bool ok = node < n;
      int nn = ok ? node : 0;
      float dv = dinv[nn];
      #pragma unroll
      for (int o = 0; o < 4; ++o) {
        float v = fmaxf(acc[m][o][r] + b0v[o], 0.f);
        if (ok) {
          size_t idx = (size_t)nn * Hd + o * 16 + lrow;
          h0r[idx] = f2bf(v);
          gr[idx]  = f2bf(v * dv);
        }
      }
    }
  }
}

// ---------------- aggregation + support ----------------
// Full-row gathers: node row = 128 B bf16, 8 lanes x uint4 (16 B). Wave = one
// degree-sorted 8-node window; per iter each slot gathers 2 edges (2-deep pipe,
// 2 KB in flight per wave). sup = bf16(0.9*dinv*(sum g[src] + g[i]) + 0.1*h0[i]).

__global__ __launch_bounds__(256) void agg_kernel(const ushort* __restrict__ gr,
                                                  const ushort* __restrict__ h0r,
                                                  const int* __restrict__ row_ptr,
                                                  const int* __restrict__ esrc,
                                                  const float* __restrict__ dinv,
                                                  const int* __restrict__ worklist,
                                                  ushort* __restrict__ supr,
                                                  int n) {
  int lane = threadIdx.x & 63;
  int ln8  = lane & 7;     // 16B piece within 128B row
  int grp  = lane >> 3;    // node slot 0..7
  int wv   = blockIdx.x * 4 + (threadIdx.x >> 6);
  int nwv  = gridDim.x * 4;
  const uint4* gu = (const uint4*)gr;
  const uint4* hu = (const uint4*)h0r;
  uint4*       su = (uint4*)supr;

  int nwin = (n + 7) >> 3;
  for (int w = wv; w < nwin; w += nwv) {
    int node = __builtin_nontemporal_load(worklist + w * 8 + grp);
    bool ok = node < n;
    int nn = ok ? node : (n - 1);
    int e    = row_ptr[nn];
    int eend = ok ? row_ptr[nn + 1] : e;
    uint4 us = gu[(size_t)nn * 8 + ln8];
    float a0 = bflo(us.x), a1 = bfhi(us.x), a2 = bflo(us.y), a3 = bfhi(us.y);
    float a4 = bflo(us.z), a5 = bfhi(us.z), a6 = bflo(us.w), a7 = bfhi(us.w);
    float c0 = 0.f, c1 = 0.f, c2 = 0.f, c3 = 0.f, c4 = 0.f, c5 = 0.f, c6 = 0.f, c7 = 0.f;
    int s0 = (e     < eend) ? __builtin_nontemporal_load(esrc + e)     : -1;
    int s1 = (e + 1 < eend) ? __builtin_nontemporal_load(esrc + e + 1) : -1;
    while (__any(e < eend)) {
      int t0 = (e + 2 < eend) ? __builtin_nontemporal_load(esrc + e + 2) : -1;
      int t1 = (e + 3 < eend) ? __builtin_nontemporal_load(esrc + e + 3) : -1;
      uint4 u0 = gu[(size_t)(s0 >= 0 ? s0 : 0) * 8 + ln8];
      uint4 u1 = gu[(size_t)(s1 >= 0 ? s1 : 0) * 8 + ln8];
      if (s0 < 0) u0 = make_uint4(0, 0, 0, 0);
      if (s1 < 0) u1 = make_uint4(0, 0, 0, 0);
      a0 += bflo(u0.x); a1 += bfhi(u0.x); a2 += bflo(u0.y); a3 += bfhi(u0.y);
      a4 += bflo(u0.z); a5 += bfhi(u0.z); a6 += bflo(u0.w); a7 += bfhi(u0.w);
      c0 += bflo(u1.x); c1 += bfhi(u1.x); c2 += bflo(u1.y); c3 += bfhi(u1.y);
      c4 += bflo(u1.z); c5 += bfhi(u1.z); c6 += bflo(u1.w); c7 += bfhi(u1.w);
      s0 = t0; s1 = t1; e += 2;
    }
    float di = dinv[nn];
    uint4 h = hu[(size_t)nn * 8 + ln8];
    float v0 = 0.9f * di * (a0 + c0) + 0.1f * bflo(h.x);
    float v1 = 0.9f * di * (a1 + c1) + 0.1f * bfhi(h.x);
    float v2 = 0.9f * di * (a2 + c2) + 0.1f * bflo(h.y);
    float v3 = 0.9f * di * (a3 + c3) + 0.1f * bfhi(h.y);
    float v4 = 0.9f * di * (a4 + c4) + 0.1f * bflo(h.z);
    float v5 = 0.9f * di * (a5 + c5) + 0.1f * bfhi(h.z);
    float v6 = 0.9f * di * (a6 + c6) + 0.1f * bflo(h.w);
    float v7 = 0.9f * di * (a7 + c7) + 0.1f * bfhi(h.w);
    if (ok) {
      uint4 o;
      o.x = (uint)f2bf(v0) | ((uint)f2bf(v1) << 16);
      o.y = (uint)f2bf(v2) | ((uint)f2bf(v3) << 16);
      o.z = (uint)f2bf(v4) | ((uint)f2bf(v5) << 16);
      o.w = (uint)f2bf(v6) | ((uint)f2bf(v7) << 16);
      su[(size_t)nn * 8 + ln8] = o;
    }
  }
}

// ---------------- layer matmul (MFMA), row-major ----------------

__global__ __launch_bounds__(256) void mat_kernel(const ushort* __restrict__ supr,
                                                  const float* __restrict__ dinv,
                                                  const ushort* __restrict__ WT,
                                                  ushort* __restrict__ goutr,
                                                  int n) {
  int wave = threadIdx.x >> 6;
  int lane = threadIdx.x & 63;
  int lrow = lane & 15;
  int lk   = lane >> 4;
  int nb   = blockIdx.x * 128 + wave * 32;

  bfrag b[4][2];
  #pragma unroll
  for (int o = 0; o < 4; ++o)
    #pragma unroll
    for (int s = 0; s < 2; ++s)
      b[o][s] = *(const bfrag*)(WT + (size_t)(o * 16 + lrow) * 64 + s * 32 + lk * 8);

  floatx4 acc[2][4];
  #pragma unroll
  for (int m = 0; m < 2; ++m)
    #pragma unroll
    for (int o = 0; o < 4; ++o) acc[m][o] = floatx4{0.f, 0.f, 0.f, 0.f};

  #pragma unroll
  for (int m = 0; m < 2; ++m) {
    int node = nb + m * 16 + lrow; if (node >= n) node = n - 1;
    bfrag a0 = *(const bfrag*)(supr + (size_t)node * Hd + lk * 8);
    bfrag a1 = *(const bfrag*)(supr + (size_t)node * Hd + 32 + lk * 8);
    #pragma unroll
    for (int o = 0; o < 4; ++o) {
      acc[m][o] = __builtin_amdgcn_mfma_f32_16x16x32_bf16(a0, b[o][0], acc[m][o], 0, 0, 0);
      acc[m][o] = __builtin_amdgcn_mfma_f32_16x16x32_bf16(a1, b[o][1], acc[m][o], 0, 0, 0);
    }
  }

  #pragma unroll
  for (int m = 0; m < 2; ++m) {
    #pragma unroll
    for (int r = 0; r < 4; ++r) {
      int node = nb + m * 16 + lk * 4 + r;
      bool ok = node < n;
      int nn = ok ? node : 0;
      float dv = dinv[nn];
      #pragma unroll
      for (int o = 0; o < 4; ++o) {
        float v = fmaxf(acc[m][o][r], 0.f);
        if (ok) goutr[(size_t)nn * Hd + o * 16 + lrow] = f2bf(v * dv);
      }
    }
  }
}

// ---------------- head ----------------

__global__ __launch_bounds__(256) void final_kernel(const ushort* __restrict__ gr,
                                                    const int* __restrict__ outdeg,
                                                    const float* __restrict__ wf,
                                                    const float* __restrict__ bfv,
                                                    float* __restrict__ out, int n) {
  int lane = threadIdx.x & 63;
  int c = (lane < Cd) ? lane : 0;
  int gw = (int)((blockIdx.x * blockDim.x + threadIdx.x) >> 6);
  int nw = (int)((gridDim.x * blockDim.x) >> 6);
  for (int i = gw; i < n; i += nw) {
    float rdi = sqrtf((float)(outdeg[i] + 1));
    float hv = bf2f(gr[(size_t)i * Hd + lane]) * rdi;
    float acc = 0.f;
    #pragma unroll
    for (int k = 0; k < 64; ++k) acc += bcast(hv, k) * wf[k * Cd + c];
    float logit = acc + bfv[c];
    float m = (lane < Cd) ? logit : -1e30f;
    #pragma unroll
    for (int off = 32; off; off >>= 1) m = fmaxf(m, __shfl_xor(m, off, 64));
    float p = (lane < Cd) ? __expf(logit - m) : 0.f;
    #pragma unroll
    for (int off = 32; off; off >>= 1) p += __shfl_xor(p, off, 64);
    float lse = m + logf(p);
    if (lane < Cd) out[(size_t)i * Cd + lane] = logit - lse;
  }
}

// ---------------- launch ----------------

extern "C" void kernel_launch(void* const* d_in, const int* in_sizes, int n_in,
                              void* d_out, int out_size, void* d_ws, size_t ws_size,
                              hipStream_t stream) {
  const float* x  = (const float*)d_in[0];
  const int*   ei = (const int*)d_in[1];
  const float* w0 = (const float*)d_in[2];
  const float* b0 = (const float*)d_in[3];
  const float* wl = (const float*)d_in[4];
  const float* wf = (const float*)d_in[5];
  const float* bf = (const float*)d_in[6];
  int N = in_sizes[0] / Fd;
  int E = in_sizes[1] / 2;
  int L = in_sizes[4] / (Hd * Hd);
  float* out = (float*)d_out;

  char* w = (char*)d_ws;
  auto alloc = [&](size_t bytes) { char* p = w; w += (bytes + 255) & ~255ULL; return p; };
  int Npad = (N + 255) & ~255;
  int RH = (N + 1) / 2;
  int NW = (RH + 3) / 4;
  int CH = (E + 31) / 32;
  int*    outdeg   = (int*)alloc((size_t)N * 4);
  int*    indeg    = (int*)alloc((size_t)N * 4);
  int*    row_ptr  = (int*)alloc((size_t)(N + 1) * 4);
  int*    cursor   = (int*)alloc((size_t)N * 4);
  float*  dinv     = (float*)alloc((size_t)N * 4);
  int*    bsum     = (int*)alloc(1024);
  int*    boff     = (int*)alloc(1024);
  int*    worklist = (int*)alloc((size_t)Npad * 4);
  uint*   partials = (uint*)alloc((size_t)128 * NW * 4);
  int*    esrc     = (int*)alloc((size_t)E * 4);
  ushort* w0T      = (ushort*)alloc((size_t)Hd * Fd * 2);
  ushort* WTall    = (ushort*)alloc((size_t)L * Hd * Hd * 2);
  ushort* h0r      = (ushort*)alloc((size_t)N * Hd * 2);
  ushort* gA       = (ushort*)alloc((size_t)N * Hd * 2);
  ushort* gB       = (ushort*)alloc((size_t)N * Hd * 2);
  ushort* supr     = (ushort*)alloc((size_t)N * Hd * 2);

  int tb = 256;
  int nb = (N + PCHUNK - 1) / PCHUNK;

  if (NW <= 12544) {
    hist_kernel<<<128, 256, 0, stream>>>(ei, E, partials, N, RH, NW, CH);
    degred_kernel<<<(N + 255) / 256, 256, 0, stream>>>(partials, N, RH, NW,
                                                       indeg, outdeg, dinv);
  } else {
    hipMemsetAsync(outdeg, 0, (size_t)N * 4, stream);
    hipMemsetAsync(indeg,  0, (size_t)N * 4, stream);
    count_fallback<<<(E + tb - 1) / tb, tb, 0, stream>>>(ei, E, outdeg, indeg);
    dinv_fallback<<<(N + tb - 1) / tb, tb, 0, stream>>>(outdeg, dinv, N);
  }
  pp_bsum<<<nb, 256, 0, stream>>>(indeg, N, bsum);
  pp_bscan<<<1, 256, 0, stream>>>(bsum, nb, boff, row_ptr, N);
  pp_scan<<<nb, 256, 0, stream>>>(indeg, N, boff, row_ptr, cursor);
  scatter_kernel<<<2048, tb, 0, stream>>>(ei, E, cursor, esrc, N);
  sortwin_kernel<<<(Npad + 255) / 256, 256, 0, stream>>>(indeg, worklist, N);

  w0prep<<<(Hd * Fd + 255) / 256, 256, 0, stream>>>(w0, w0T);
  wprep<<<(L * Hd * Hd + 255) / 256, 256, 0, stream>>>(wl, WTall, L);

  int gemm_grid = (N + 127) / 128;
  gin_kernel<<<gemm_grid, 256, 0, stream>>>(x, w0T, b0, dinv, h0r, gA, N);

  ushort* cur = gA;
  ushort* bufs[2] = {gB, gA};
  for (int l = 0; l < L; ++l) {
    ushort* nxt = bufs[l & 1];
    agg_kernel<<<1024, 256, 0, stream>>>(cur, h0r, row_ptr, esrc, dinv, worklist,
                                         supr, N);
    mat_kernel<<<gemm_grid, 256, 0, stream>>>(supr, dinv, WTall + (size_t)l * Hd * Hd, nxt, N);
    cur = nxt;
  }
  final_kernel<<<2048, 256, 0, stream>>>(cur, outdeg, wf, bf, out, N);
}